// Round 1
// baseline (518.937 us; speedup 1.0000x reference)
//
#include <hip/hip_runtime.h>
#include <hip/hip_bf16.h>

// MultiHeadAttention fwd: B=2 S=2048 D=2048 H=16 DH=128, causal, fp32 in/out.
// Strategy: bf16 MFMA everywhere (no fp32 MFMA on CDNA4), fp32 accum.
//   cast -> fused QKV gemm (B^T form) -> V transpose -> flash attn -> out gemm.
// Workspace layout (bytes), total 117,440,512:
//   WQKV 0        : 3*D*D*2 = 25165824   (wq;wk;wv rows, bf16)
//   WO   25165824 : D*D*2   = 8388608
//   XB   33554432 : M*D*2   = 16777216   (x bf16; ALIASED later by attn-out)
//   Qb   50331648 : 16777216             ([B,H,S,DH] bf16, pre-scaled 1/sqrt(DH))
//   Kb   67108864 : 16777216
//   Vb   83886080 : 16777216
//   VT  100663296 : 16777216             ([B,H,DH,S] bf16)

using u16 = unsigned short;
typedef float  f32x4  __attribute__((ext_vector_type(4)));
typedef short  short8 __attribute__((ext_vector_type(8)));

#define DEV __device__ __forceinline__

constexpr int Bc = 2, Sc = 2048, Dc = 2048, Hc = 16, DHc = 128, Mc = 4096, Kc = 2048;
constexpr float RSCALE = 0.08838834764831845f;   // 1/sqrt(128)
constexpr float L2E    = 1.44269504088896341f;

DEV u16 f2bf(float f) { __bf16 h = (__bf16)f; return __builtin_bit_cast(u16, h); }

DEV void gload_lds16(const void* gsrc, void* lds) {
  __builtin_amdgcn_global_load_lds(
      (const __attribute__((address_space(1))) unsigned int*)gsrc,
      (__attribute__((address_space(3))) unsigned int*)lds, 16, 0, 0);
}

// ---------------- fp32 -> bf16 cast ----------------
__global__ void cast_bf16(const float* __restrict__ in, u16* __restrict__ out, int n4) {
  int i = blockIdx.x * blockDim.x + threadIdx.x;
  if (i >= n4) return;
  float4 v = ((const float4*)in)[i];
  u16 o0 = f2bf(v.x), o1 = f2bf(v.y), o2 = f2bf(v.z), o3 = f2bf(v.w);
  u16* p = out + i * 4;
  p[0] = o0; p[1] = o1; p[2] = o2; p[3] = o3;
}

// ---------------- GEMM: C[m,n] = sum_k A[m,k]*W[n,k]  (A,W bf16 row-major) ---
// 128x128 tile, BK=32, 4 waves (2x2, each 64x64 = 4x4 16x16x32 frags),
// double-buffered LDS staged via global_load_lds w=16, chunk-XOR swizzle on
// the GLOBAL source (LDS dest linear, rule #21). EPI 0: QKV scatter. 1: fp32+bias.
template <int EPI>
__global__ __launch_bounds__(256) void gemm_bt(
    const u16* __restrict__ A, const u16* __restrict__ W,
    const float* __restrict__ bias0, const float* __restrict__ bias1,
    const float* __restrict__ bias2,
    u16* __restrict__ q_out, u16* __restrict__ k_out, u16* __restrict__ v_out,
    float* __restrict__ f_out) {
  __shared__ u16 lsA[2][128 * 32];
  __shared__ u16 lsB[2][128 * 32];
  const int tid = threadIdx.x;
  const int lane = tid & 63;
  const int w = tid >> 6;
  const int wr = w >> 1, wc = w & 1;
  const int l15 = lane & 15, l4 = lane >> 4;
  const int m0 = blockIdx.y * 128;
  const int n0 = blockIdx.x * 128;

  f32x4 acc[4][4] = {};

  auto stage = [&](int buf, int t) {
    const int k0 = t * 32;
#pragma unroll
    for (int c = 0; c < 2; ++c) {
      int p = c * 256 + tid;              // 16B chunk id, 512 per tile
      int row = p >> 2;
      int lg = (p & 3) ^ (row & 3);       // logical chunk for this phys slot
      gload_lds16(A + (size_t)(m0 + row) * Kc + k0 + lg * 8, &lsA[buf][p * 8]);
    }
#pragma unroll
    for (int c = 0; c < 2; ++c) {
      int p = c * 256 + tid;
      int row = p >> 2;
      int lg = (p & 3) ^ (row & 3);
      gload_lds16(W + (size_t)(n0 + row) * Kc + k0 + lg * 8, &lsB[buf][p * 8]);
    }
  };

  auto compute = [&](int buf) {
    short8 af[4], bf[4];
#pragma unroll
    for (int mf = 0; mf < 4; ++mf) {
      int row = wr * 64 + mf * 16 + l15;
      int pc = l4 ^ (row & 3);
      af[mf] = *(const short8*)&lsA[buf][row * 32 + pc * 8];
    }
#pragma unroll
    for (int nf = 0; nf < 4; ++nf) {
      int row = wc * 64 + nf * 16 + l15;
      int pc = l4 ^ (row & 3);
      bf[nf] = *(const short8*)&lsB[buf][row * 32 + pc * 8];
    }
#pragma unroll
    for (int mf = 0; mf < 4; ++mf)
#pragma unroll
      for (int nf = 0; nf < 4; ++nf)
        acc[mf][nf] = __builtin_amdgcn_mfma_f32_16x16x32_bf16(af[mf], bf[nf], acc[mf][nf], 0, 0, 0);
  };

  stage(0, 0);
  __syncthreads();
  int buf = 0;
  const int NT = Kc / 32;
  for (int t = 0; t < NT - 1; ++t) {
    stage(buf ^ 1, t + 1);
    compute(buf);
    __syncthreads();
    buf ^= 1;
  }
  compute(buf);

  // epilogue: C/D layout col=lane&15, row=(lane>>4)*4+reg  [m89/m91 verified]
  if constexpr (EPI == 0) {
#pragma unroll
    for (int nf = 0; nf < 4; ++nf) {
      const int n = n0 + wc * 64 + nf * 16 + l15;
      const int sec = n >> 11;            // 0:Q 1:K 2:V (uniform per block)
      const int n2 = n & 2047;
      const float bias = sec == 0 ? bias0[n2] : (sec == 1 ? bias1[n2] : bias2[n2]);
      const float scl = sec == 0 ? RSCALE : 1.0f;
      u16* dst = sec == 0 ? q_out : (sec == 1 ? k_out : v_out);
      const int h = n2 >> 7, dh = n2 & 127;
#pragma unroll
      for (int mf = 0; mf < 4; ++mf)
#pragma unroll
        for (int r = 0; r < 4; ++r) {
          const int m = m0 + wr * 64 + mf * 16 + l4 * 4 + r;
          const int bb = m >> 11, s = m & 2047;
          dst[((size_t)(bb * Hc + h) * Sc + s) * DHc + dh] = f2bf((acc[mf][nf][r] + bias) * scl);
        }
    }
  } else {
#pragma unroll
    for (int nf = 0; nf < 4; ++nf) {
      const int n = n0 + wc * 64 + nf * 16 + l15;
      const float bias = bias0[n];
#pragma unroll
      for (int mf = 0; mf < 4; ++mf)
#pragma unroll
        for (int r = 0; r < 4; ++r) {
          const int m = m0 + wr * 64 + mf * 16 + l4 * 4 + r;
          f_out[(size_t)m * Dc + n] = acc[mf][nf][r] + bias;
        }
    }
  }
}

// ---------------- V transpose: [B,H,S,DH] -> [B,H,DH,S] ----------------
__global__ void transpose_v(const u16* __restrict__ V, u16* __restrict__ VT) {
  __shared__ u16 t[32][33];
  const int bh = blockIdx.z;
  const int s0 = blockIdx.x * 32;
  const int d0 = blockIdx.y * 32;
  const int tx = threadIdx.x, ty = threadIdx.y;   // 32 x 8
#pragma unroll
  for (int k = 0; k < 4; ++k)
    t[ty + 8 * k][tx] = V[((size_t)bh * Sc + s0 + ty + 8 * k) * DHc + d0 + tx];
  __syncthreads();
#pragma unroll
  for (int k = 0; k < 4; ++k)
    VT[((size_t)bh * DHc + d0 + ty + 8 * k) * Sc + s0 + tx] = t[tx][ty + 8 * k];
}

// ---------------- flash attention (causal) ----------------
// 4 waves x 16 Q-rows = 64-row Q tile per block; KVBLK=64; Q pre-scaled.
// K tile [64][128] and VT tile [128][64] staged with XOR-chunk source swizzle.
__global__ __launch_bounds__(256) void fattn(
    const u16* __restrict__ Qb, const u16* __restrict__ Kb,
    const u16* __restrict__ VTb, u16* __restrict__ AO) {
  __shared__ u16 lsK[64 * 128];
  __shared__ u16 lsV[128 * 64];
  __shared__ u16 lsP[4][16 * 64];

  const int tid = threadIdx.x;
  const int lane = tid & 63;
  const int w = tid >> 6;
  const int l15 = lane & 15, l4 = lane >> 4;
  const int bh = blockIdx.y;
  const int qt = (int)gridDim.x - 1 - (int)blockIdx.x;  // longest blocks first
  const int q0 = qt * 64;

  // Q fragments in registers: rows q0 + w*16 + l15, A-frag k-chunk = l4
  const size_t qbase = ((size_t)bh * Sc + q0 + w * 16 + l15) * DHc;
  short8 qf[4];
#pragma unroll
  for (int ks = 0; ks < 4; ++ks)
    qf[ks] = *(const short8*)&Qb[qbase + ks * 32 + l4 * 8];

  float m_run[4], l_run[4];
#pragma unroll
  for (int r = 0; r < 4; ++r) { m_run[r] = -__builtin_inff(); l_run[r] = 0.f; }
  f32x4 o_acc[8] = {};

  const int ntiles = qt + 1;
  for (int ti = 0; ti < ntiles; ++ti) {
    const int kv0 = ti * 64;
    __syncthreads();   // previous tile's LDS reads done
    // stage K tile: 64 rows x 256B (16 chunks/row, XOR low3 of chunk with row&7)
#pragma unroll
    for (int c = 0; c < 4; ++c) {
      int p = c * 256 + tid;                     // 1024 chunks
      int row = p >> 4, ph = p & 15;
      int lg = (ph & 8) | ((ph ^ row) & 7);
      gload_lds16(Kb + ((size_t)bh * Sc + kv0 + row) * DHc + lg * 8, &lsK[p * 8]);
    }
    // stage VT tile: 128 rows x 128B (8 chunks/row)
#pragma unroll
    for (int c = 0; c < 4; ++c) {
      int p = c * 256 + tid;
      int row = p >> 3, ph = p & 7;
      int lg = ph ^ (row & 7);
      gload_lds16(VTb + ((size_t)bh * DHc + row) * Sc + kv0 + lg * 8, &lsV[p * 8]);
    }
    __syncthreads();

    // S = Q K^T  (scores; scale already folded into Q)
    f32x4 s[4] = {};
#pragma unroll
    for (int nf = 0; nf < 4; ++nf) {
      int row = nf * 16 + l15;
#pragma unroll
      for (int ks = 0; ks < 4; ++ks) {
        int lg = ks * 4 + l4;
        int pc = (lg & 8) | ((lg ^ row) & 7);
        short8 kf = *(const short8*)&lsK[row * 128 + pc * 8];
        s[nf] = __builtin_amdgcn_mfma_f32_16x16x32_bf16(qf[ks], kf, s[nf], 0, 0, 0);
      }
    }
    if (kv0 == q0) {  // diagonal tile: mask kv>q
#pragma unroll
      for (int nf = 0; nf < 4; ++nf) {
        int kc = nf * 16 + l15;
#pragma unroll
        for (int r = 0; r < 4; ++r)
          if (kc > w * 16 + l4 * 4 + r) s[nf][r] = -__builtin_inff();
      }
    }
    // online softmax: rows live in 16-lane groups (lanes sharing l>>4... row = l4*4+r)
    float alpha[4];
#pragma unroll
    for (int r = 0; r < 4; ++r) {
      float mx = fmaxf(fmaxf(s[0][r], s[1][r]), fmaxf(s[2][r], s[3][r]));
      mx = fmaxf(mx, __shfl_xor(mx, 1));
      mx = fmaxf(mx, __shfl_xor(mx, 2));
      mx = fmaxf(mx, __shfl_xor(mx, 4));
      mx = fmaxf(mx, __shfl_xor(mx, 8));
      float mnew = fmaxf(m_run[r], mx);
      alpha[r] = __builtin_amdgcn_exp2f((m_run[r] - mnew) * L2E);
      m_run[r] = mnew;
    }
#pragma unroll
    for (int nf = 0; nf < 4; ++nf)
#pragma unroll
      for (int r = 0; r < 4; ++r)
        s[nf][r] = __builtin_amdgcn_exp2f((s[nf][r] - m_run[r]) * L2E);
#pragma unroll
    for (int r = 0; r < 4; ++r) {
      float sm = s[0][r] + s[1][r] + s[2][r] + s[3][r];
      sm += __shfl_xor(sm, 1);
      sm += __shfl_xor(sm, 2);
      sm += __shfl_xor(sm, 4);
      sm += __shfl_xor(sm, 8);
      l_run[r] = l_run[r] * alpha[r] + sm;
    }
#pragma unroll
    for (int nf2 = 0; nf2 < 8; ++nf2)
#pragma unroll
      for (int r = 0; r < 4; ++r) o_acc[nf2][r] *= alpha[r];

    // P -> bf16 -> swizzled per-wave LDS ([16][64], 8 chunks/row XOR row&7)
#pragma unroll
    for (int nf = 0; nf < 4; ++nf)
#pragma unroll
      for (int r = 0; r < 4; ++r) {
        int rif = l4 * 4 + r;
        int kc = nf * 16 + l15;
        int pc = (kc >> 3) ^ (rif & 7);
        lsP[w][rif * 64 + pc * 8 + (kc & 7)] = f2bf(s[nf][r]);
      }
    asm volatile("s_waitcnt lgkmcnt(0)" ::: "memory");  // P writes -> P reads, same wave

    // O += P V  (A=P from LDS, B=V from swizzled VT tile)
#pragma unroll
    for (int ks = 0; ks < 2; ++ks) {
      int pc = (ks * 4 + l4) ^ (l15 & 7);
      short8 pa = *(const short8*)&lsP[w][l15 * 64 + pc * 8];
#pragma unroll
      for (int nf2 = 0; nf2 < 8; ++nf2) {
        int vrow = nf2 * 16 + l15;
        int vpc = (ks * 4 + l4) ^ (vrow & 7);
        short8 vb = *(const short8*)&lsV[vrow * 64 + vpc * 8];
        o_acc[nf2] = __builtin_amdgcn_mfma_f32_16x16x32_bf16(pa, vb, o_acc[nf2], 0, 0, 0);
      }
    }
  }

  // epilogue: AO[b, s, h*DH+d] bf16
  const int b = bh >> 4, h = bh & 15;
#pragma unroll
  for (int nf2 = 0; nf2 < 8; ++nf2)
#pragma unroll
    for (int r = 0; r < 4; ++r) {
      int qr = q0 + w * 16 + l4 * 4 + r;
      float ov = o_acc[nf2][r] / l_run[r];
      AO[((size_t)(b * Sc + qr)) * Dc + h * DHc + nf2 * 16 + l15] = f2bf(ov);
    }
}

// ---------------- launch ----------------
extern "C" void kernel_launch(void* const* d_in, const int* in_sizes, int n_in,
                              void* d_out, int out_size, void* d_ws, size_t ws_size,
                              hipStream_t stream) {
  const float* x  = (const float*)d_in[0];
  // d_in[1] = mask (bool) — causal, known statically; unused
  const float* wq = (const float*)d_in[2];
  const float* bq = (const float*)d_in[3];
  const float* wk = (const float*)d_in[4];
  const float* bk = (const float*)d_in[5];
  const float* wv = (const float*)d_in[6];
  const float* bv = (const float*)d_in[7];
  const float* wo = (const float*)d_in[8];
  const float* bo = (const float*)d_in[9];
  float* out = (float*)d_out;

  char* ws = (char*)d_ws;
  u16* WQKV = (u16*)(ws + 0);
  u16* WOb  = (u16*)(ws + 25165824);
  u16* XB   = (u16*)(ws + 33554432);
  u16* Qb   = (u16*)(ws + 50331648);
  u16* Kb   = (u16*)(ws + 67108864);
  u16* Vb   = (u16*)(ws + 83886080);
  u16* VTb  = (u16*)(ws + 100663296);
  u16* AO   = XB;   // x_bf16 dead after QKV gemm; reuse for attention output

  cast_bf16<<<dim3(8192), dim3(256), 0, stream>>>(x, XB, Mc * Dc / 4);
  cast_bf16<<<dim3(4096), dim3(256), 0, stream>>>(wq, WQKV, Dc * Dc / 4);
  cast_bf16<<<dim3(4096), dim3(256), 0, stream>>>(wk, WQKV + (size_t)Dc * Dc, Dc * Dc / 4);
  cast_bf16<<<dim3(4096), dim3(256), 0, stream>>>(wv, WQKV + (size_t)2 * Dc * Dc, Dc * Dc / 4);
  cast_bf16<<<dim3(4096), dim3(256), 0, stream>>>(wo, WOb, Dc * Dc / 4);

  gemm_bt<0><<<dim3(48, 32), dim3(256), 0, stream>>>(XB, WQKV, bq, bk, bv, Qb, Kb, Vb, nullptr);
  transpose_v<<<dim3(64, 4, 32), dim3(32, 8), 0, stream>>>(Vb, VTb);
  fattn<<<dim3(32, 32), dim3(256), 0, stream>>>(Qb, Kb, VTb, AO);
  gemm_bt<1><<<dim3(16, 32), dim3(256), 0, stream>>>(AO, WOb, bo, nullptr, nullptr,
                                                     nullptr, nullptr, nullptr, out);
}

// Round 2
// 440.594 us; speedup vs baseline: 1.1778x; 1.1778x over previous
//
#include <hip/hip_runtime.h>
#include <hip/hip_bf16.h>

// MultiHeadAttention fwd: B=2 S=2048 D=2048 H=16 DH=128, causal, fp32 in/out.
// Strategy: bf16 MFMA everywhere (no fp32 MFMA on CDNA4), fp32 accum.
//   cast -> fused QKV gemm (B^T form) -> V transpose -> flash attn -> out gemm.
// R2: fattn rework — causal pair-balanced blocks (33 iters each, 512 blocks =
//     2/CU exactly), double-buffered K/V stage (T3 2-phase), XCD-clustered bh,
//     setprio around MFMA clusters.
// Workspace layout (bytes), total 117,440,512:
//   WQKV 0        : 3*D*D*2 = 25165824   (wq;wk;wv rows, bf16)
//   WO   25165824 : D*D*2   = 8388608
//   XB   33554432 : M*D*2   = 16777216   (x bf16; ALIASED later by attn-out)
//   Qb   50331648 : 16777216             ([B,H,S,DH] bf16, pre-scaled 1/sqrt(DH))
//   Kb   67108864 : 16777216
//   Vb   83886080 : 16777216
//   VT  100663296 : 16777216             ([B,H,DH,S] bf16)

using u16 = unsigned short;
typedef float  f32x4  __attribute__((ext_vector_type(4)));
typedef short  short8 __attribute__((ext_vector_type(8)));

#define DEV __device__ __forceinline__

constexpr int Bc = 2, Sc = 2048, Dc = 2048, Hc = 16, DHc = 128, Mc = 4096, Kc = 2048;
constexpr float RSCALE = 0.08838834764831845f;   // 1/sqrt(128)
constexpr float L2E    = 1.44269504088896341f;

DEV u16 f2bf(float f) { __bf16 h = (__bf16)f; return __builtin_bit_cast(u16, h); }

DEV void gload_lds16(const void* gsrc, void* lds) {
  __builtin_amdgcn_global_load_lds(
      (const __attribute__((address_space(1))) unsigned int*)gsrc,
      (__attribute__((address_space(3))) unsigned int*)lds, 16, 0, 0);
}

// ---------------- fp32 -> bf16 cast ----------------
__global__ void cast_bf16(const float* __restrict__ in, u16* __restrict__ out, int n4) {
  int i = blockIdx.x * blockDim.x + threadIdx.x;
  if (i >= n4) return;
  float4 v = ((const float4*)in)[i];
  u16 o0 = f2bf(v.x), o1 = f2bf(v.y), o2 = f2bf(v.z), o3 = f2bf(v.w);
  u16* p = out + i * 4;
  p[0] = o0; p[1] = o1; p[2] = o2; p[3] = o3;
}

// ---------------- GEMM: C[m,n] = sum_k A[m,k]*W[n,k]  (A,W bf16 row-major) ---
// 128x128 tile, BK=32, 4 waves (2x2, each 64x64 = 4x4 16x16x32 frags),
// double-buffered LDS staged via global_load_lds w=16, chunk-XOR swizzle on
// the GLOBAL source (LDS dest linear, rule #21). EPI 0: QKV scatter. 1: fp32+bias.
template <int EPI>
__global__ __launch_bounds__(256) void gemm_bt(
    const u16* __restrict__ A, const u16* __restrict__ W,
    const float* __restrict__ bias0, const float* __restrict__ bias1,
    const float* __restrict__ bias2,
    u16* __restrict__ q_out, u16* __restrict__ k_out, u16* __restrict__ v_out,
    float* __restrict__ f_out) {
  __shared__ u16 lsA[2][128 * 32];
  __shared__ u16 lsB[2][128 * 32];
  const int tid = threadIdx.x;
  const int lane = tid & 63;
  const int w = tid >> 6;
  const int wr = w >> 1, wc = w & 1;
  const int l15 = lane & 15, l4 = lane >> 4;
  const int m0 = blockIdx.y * 128;
  const int n0 = blockIdx.x * 128;

  f32x4 acc[4][4] = {};

  auto stage = [&](int buf, int t) {
    const int k0 = t * 32;
#pragma unroll
    for (int c = 0; c < 2; ++c) {
      int p = c * 256 + tid;              // 16B chunk id, 512 per tile
      int row = p >> 2;
      int lg = (p & 3) ^ (row & 3);       // logical chunk for this phys slot
      gload_lds16(A + (size_t)(m0 + row) * Kc + k0 + lg * 8, &lsA[buf][p * 8]);
    }
#pragma unroll
    for (int c = 0; c < 2; ++c) {
      int p = c * 256 + tid;
      int row = p >> 2;
      int lg = (p & 3) ^ (row & 3);
      gload_lds16(W + (size_t)(n0 + row) * Kc + k0 + lg * 8, &lsB[buf][p * 8]);
    }
  };

  auto compute = [&](int buf) {
    short8 af[4], bf[4];
#pragma unroll
    for (int mf = 0; mf < 4; ++mf) {
      int row = wr * 64 + mf * 16 + l15;
      int pc = l4 ^ (row & 3);
      af[mf] = *(const short8*)&lsA[buf][row * 32 + pc * 8];
    }
#pragma unroll
    for (int nf = 0; nf < 4; ++nf) {
      int row = wc * 64 + nf * 16 + l15;
      int pc = l4 ^ (row & 3);
      bf[nf] = *(const short8*)&lsB[buf][row * 32 + pc * 8];
    }
#pragma unroll
    for (int mf = 0; mf < 4; ++mf)
#pragma unroll
      for (int nf = 0; nf < 4; ++nf)
        acc[mf][nf] = __builtin_amdgcn_mfma_f32_16x16x32_bf16(af[mf], bf[nf], acc[mf][nf], 0, 0, 0);
  };

  stage(0, 0);
  __syncthreads();
  int buf = 0;
  const int NT = Kc / 32;
  for (int t = 0; t < NT - 1; ++t) {
    stage(buf ^ 1, t + 1);
    compute(buf);
    __syncthreads();
    buf ^= 1;
  }
  compute(buf);

  // epilogue: C/D layout col=lane&15, row=(lane>>4)*4+reg  [m89/m91 verified]
  if constexpr (EPI == 0) {
#pragma unroll
    for (int nf = 0; nf < 4; ++nf) {
      const int n = n0 + wc * 64 + nf * 16 + l15;
      const int sec = n >> 11;            // 0:Q 1:K 2:V (uniform per block)
      const int n2 = n & 2047;
      const float bias = sec == 0 ? bias0[n2] : (sec == 1 ? bias1[n2] : bias2[n2]);
      const float scl = sec == 0 ? RSCALE : 1.0f;
      u16* dst = sec == 0 ? q_out : (sec == 1 ? k_out : v_out);
      const int h = n2 >> 7, dh = n2 & 127;
#pragma unroll
      for (int mf = 0; mf < 4; ++mf)
#pragma unroll
        for (int r = 0; r < 4; ++r) {
          const int m = m0 + wr * 64 + mf * 16 + l4 * 4 + r;
          const int bb = m >> 11, s = m & 2047;
          dst[((size_t)(bb * Hc + h) * Sc + s) * DHc + dh] = f2bf((acc[mf][nf][r] + bias) * scl);
        }
    }
  } else {
#pragma unroll
    for (int nf = 0; nf < 4; ++nf) {
      const int n = n0 + wc * 64 + nf * 16 + l15;
      const float bias = bias0[n];
#pragma unroll
      for (int mf = 0; mf < 4; ++mf)
#pragma unroll
        for (int r = 0; r < 4; ++r) {
          const int m = m0 + wr * 64 + mf * 16 + l4 * 4 + r;
          f_out[(size_t)m * Dc + n] = acc[mf][nf][r] + bias;
        }
    }
  }
}

// ---------------- V transpose: [B,H,S,DH] -> [B,H,DH,S] ----------------
__global__ void transpose_v(const u16* __restrict__ V, u16* __restrict__ VT) {
  __shared__ u16 t[32][33];
  const int bh = blockIdx.z;
  const int s0 = blockIdx.x * 32;
  const int d0 = blockIdx.y * 32;
  const int tx = threadIdx.x, ty = threadIdx.y;   // 32 x 8
#pragma unroll
  for (int k = 0; k < 4; ++k)
    t[ty + 8 * k][tx] = V[((size_t)bh * Sc + s0 + ty + 8 * k) * DHc + d0 + tx];
  __syncthreads();
#pragma unroll
  for (int k = 0; k < 4; ++k)
    VT[((size_t)bh * DHc + d0 + ty + 8 * k) * Sc + s0 + tx] = t[tx][ty + 8 * k];
}

// ---------------- flash attention (causal), R2 ----------------
// 512 blocks, 4 waves x 16 Q-rows = 64-row Q tile. Each block processes the
// causal-complementary q-tile PAIR {p, 31-p}: exactly 33 KV-tile iterations
// per block -> perfect balance, 2 blocks/CU resident throughout.
// K/V double-buffered (stage t+1 overlaps compute t, one vmcnt+barrier/iter).
// XCD clustering: all 16 pair-blocks of a bh map to one XCD (KV 1MB x 4bh = L2).
__global__ __launch_bounds__(256) void fattn(
    const u16* __restrict__ Qb, const u16* __restrict__ Kb,
    const u16* __restrict__ VTb, u16* __restrict__ AO) {
  __shared__ u16 lsK[2][64 * 128];
  __shared__ u16 lsV[2][128 * 64];
  __shared__ u16 lsP[4][16 * 64];

  const int tid = threadIdx.x;
  const int lane = tid & 63;
  const int w = tid >> 6;
  const int l15 = lane & 15, l4 = lane >> 4;

  // remap: assume linear-id round-robin over 8 XCDs -> cluster 4 bh per XCD
  const int id = blockIdx.x;
  const int xcd = id & 7, seq = id >> 3;     // seq 0..63
  const int bh = xcd + 8 * (seq >> 4);       // {xcd, xcd+8, xcd+16, xcd+24}
  const int pair = seq & 15;

  const int b = bh >> 4, h = bh & 15;
  const size_t kbase = (size_t)bh * Sc * DHc;
  const size_t vbase = (size_t)bh * DHc * Sc;

#pragma unroll 1
  for (int qsel = 0; qsel < 2; ++qsel) {
    const int qt = qsel ? (31 - pair) : pair;
    const int q0 = qt * 64;
    const int ntiles = qt + 1;

    // Q fragments in registers: rows q0 + w*16 + l15, A-frag k-chunk = l4
    const size_t qbase = ((size_t)bh * Sc + q0 + w * 16 + l15) * DHc;
    short8 qf[4];
#pragma unroll
    for (int ks = 0; ks < 4; ++ks)
      qf[ks] = *(const short8*)&Qb[qbase + ks * 32 + l4 * 8];

    float m_run[4], l_run[4];
#pragma unroll
    for (int r = 0; r < 4; ++r) { m_run[r] = -__builtin_inff(); l_run[r] = 0.f; }
    f32x4 o_acc[8] = {};

    auto stageKV = [&](int sb, int ti) {
      const int kv0 = ti * 64;
      // K tile: 64 rows x 256B (16 chunks/row, XOR low3 of chunk with row&7)
#pragma unroll
      for (int c = 0; c < 4; ++c) {
        int p = c * 256 + tid;                    // 1024 chunks
        int row = p >> 4, ph = p & 15;
        int lg = (ph & 8) | ((ph ^ row) & 7);
        gload_lds16(Kb + kbase + (size_t)(kv0 + row) * DHc + lg * 8, &lsK[sb][p * 8]);
      }
      // VT tile: 128 rows x 128B (8 chunks/row)
#pragma unroll
      for (int c = 0; c < 4; ++c) {
        int p = c * 256 + tid;
        int row = p >> 3, ph = p & 7;
        int lg = ph ^ (row & 7);
        gload_lds16(VTb + vbase + (size_t)row * Sc + kv0 + lg * 8, &lsV[sb][p * 8]);
      }
    };

    // prologue: stage tile 0
    stageKV(0, 0);
    asm volatile("s_waitcnt vmcnt(0)" ::: "memory");
    __syncthreads();

    int buf = 0;
#pragma unroll 1
    for (int ti = 0; ti < ntiles; ++ti) {
      const int kv0 = ti * 64;
      if (ti + 1 < ntiles) stageKV(buf ^ 1, ti + 1);   // overlap with compute

      // S = Q K^T  (scale pre-folded into Q)
      f32x4 s[4] = {};
      __builtin_amdgcn_s_setprio(1);
#pragma unroll
      for (int nf = 0; nf < 4; ++nf) {
        int row = nf * 16 + l15;
#pragma unroll
        for (int ks = 0; ks < 4; ++ks) {
          int lg = ks * 4 + l4;
          int pc = (lg & 8) | ((lg ^ row) & 7);
          short8 kf = *(const short8*)&lsK[buf][row * 128 + pc * 8];
          s[nf] = __builtin_amdgcn_mfma_f32_16x16x32_bf16(qf[ks], kf, s[nf], 0, 0, 0);
        }
      }
      __builtin_amdgcn_s_setprio(0);

      if (kv0 == q0) {  // diagonal tile: mask kv>q
#pragma unroll
        for (int nf = 0; nf < 4; ++nf) {
          int kc = nf * 16 + l15;
#pragma unroll
          for (int r = 0; r < 4; ++r)
            if (kc > w * 16 + l4 * 4 + r) s[nf][r] = -__builtin_inff();
        }
      }
      // online softmax: row r of the 16-lane group (lanes share l4 -> row l4*4+r)
      float alpha[4];
#pragma unroll
      for (int r = 0; r < 4; ++r) {
        float mx = fmaxf(fmaxf(s[0][r], s[1][r]), fmaxf(s[2][r], s[3][r]));
        mx = fmaxf(mx, __shfl_xor(mx, 1));
        mx = fmaxf(mx, __shfl_xor(mx, 2));
        mx = fmaxf(mx, __shfl_xor(mx, 4));
        mx = fmaxf(mx, __shfl_xor(mx, 8));
        float mnew = fmaxf(m_run[r], mx);
        alpha[r] = __builtin_amdgcn_exp2f((m_run[r] - mnew) * L2E);
        m_run[r] = mnew;
      }
#pragma unroll
      for (int nf = 0; nf < 4; ++nf)
#pragma unroll
        for (int r = 0; r < 4; ++r)
          s[nf][r] = __builtin_amdgcn_exp2f((s[nf][r] - m_run[r]) * L2E);
#pragma unroll
      for (int r = 0; r < 4; ++r) {
        float sm = s[0][r] + s[1][r] + s[2][r] + s[3][r];
        sm += __shfl_xor(sm, 1);
        sm += __shfl_xor(sm, 2);
        sm += __shfl_xor(sm, 4);
        sm += __shfl_xor(sm, 8);
        l_run[r] = l_run[r] * alpha[r] + sm;
      }
#pragma unroll
      for (int nf2 = 0; nf2 < 8; ++nf2)
#pragma unroll
        for (int r = 0; r < 4; ++r) o_acc[nf2][r] *= alpha[r];

      // P -> bf16 -> swizzled per-wave LDS ([16][64], 8-chunk rows XOR row&7)
#pragma unroll
      for (int nf = 0; nf < 4; ++nf)
#pragma unroll
        for (int r = 0; r < 4; ++r) {
          int rif = l4 * 4 + r;
          int kc = nf * 16 + l15;
          int pc = (kc >> 3) ^ (rif & 7);
          lsP[w][rif * 64 + pc * 8 + (kc & 7)] = f2bf(s[nf][r]);
        }
      asm volatile("s_waitcnt lgkmcnt(0)" ::: "memory");  // same-wave P w->r

      // O += P V  (A=P from LDS, B=V from swizzled VT tile)
      __builtin_amdgcn_s_setprio(1);
#pragma unroll
      for (int ks = 0; ks < 2; ++ks) {
        int pc = (ks * 4 + l4) ^ (l15 & 7);
        short8 pa = *(const short8*)&lsP[w][l15 * 64 + pc * 8];
#pragma unroll
        for (int nf2 = 0; nf2 < 8; ++nf2) {
          int vrow = nf2 * 16 + l15;
          int vpc = (ks * 4 + l4) ^ (vrow & 7);
          short8 vb = *(const short8*)&lsV[buf][vrow * 64 + vpc * 8];
          o_acc[nf2] = __builtin_amdgcn_mfma_f32_16x16x32_bf16(pa, vb, o_acc[nf2], 0, 0, 0);
        }
      }
      __builtin_amdgcn_s_setprio(0);

      // staged loads for t+1 landed; all waves done reading buf
      asm volatile("s_waitcnt vmcnt(0)" ::: "memory");
      __syncthreads();
      buf ^= 1;
    }

    // epilogue: AO[b, s, h*DH+d] bf16
#pragma unroll
    for (int nf2 = 0; nf2 < 8; ++nf2)
#pragma unroll
      for (int r = 0; r < 4; ++r) {
        int qr = q0 + w * 16 + l4 * 4 + r;
        float ov = o_acc[nf2][r] / l_run[r];
        AO[((size_t)(b * Sc + qr)) * Dc + h * DHc + nf2 * 16 + l15] = f2bf(ov);
      }
    __syncthreads();   // LDS reuse safety across qsel
  }
}

// ---------------- launch ----------------
extern "C" void kernel_launch(void* const* d_in, const int* in_sizes, int n_in,
                              void* d_out, int out_size, void* d_ws, size_t ws_size,
                              hipStream_t stream) {
  const float* x  = (const float*)d_in[0];
  // d_in[1] = mask (bool) — causal, known statically; unused
  const float* wq = (const float*)d_in[2];
  const float* bq = (const float*)d_in[3];
  const float* wk = (const float*)d_in[4];
  const float* bk = (const float*)d_in[5];
  const float* wv = (const float*)d_in[6];
  const float* bv = (const float*)d_in[7];
  const float* wo = (const float*)d_in[8];
  const float* bo = (const float*)d_in[9];
  float* out = (float*)d_out;

  char* ws = (char*)d_ws;
  u16* WQKV = (u16*)(ws + 0);
  u16* WOb  = (u16*)(ws + 25165824);
  u16* XB   = (u16*)(ws + 33554432);
  u16* Qb   = (u16*)(ws + 50331648);
  u16* Kb   = (u16*)(ws + 67108864);
  u16* Vb   = (u16*)(ws + 83886080);
  u16* VTb  = (u16*)(ws + 100663296);
  u16* AO   = XB;   // x_bf16 dead after QKV gemm; reuse for attention output

  cast_bf16<<<dim3(8192), dim3(256), 0, stream>>>(x, XB, Mc * Dc / 4);
  cast_bf16<<<dim3(4096), dim3(256), 0, stream>>>(wq, WQKV, Dc * Dc / 4);
  cast_bf16<<<dim3(4096), dim3(256), 0, stream>>>(wk, WQKV + (size_t)Dc * Dc, Dc * Dc / 4);
  cast_bf16<<<dim3(4096), dim3(256), 0, stream>>>(wv, WQKV + (size_t)2 * Dc * Dc, Dc * Dc / 4);
  cast_bf16<<<dim3(4096), dim3(256), 0, stream>>>(wo, WOb, Dc * Dc / 4);

  gemm_bt<0><<<dim3(48, 32), dim3(256), 0, stream>>>(XB, WQKV, bq, bk, bv, Qb, Kb, Vb, nullptr);
  transpose_v<<<dim3(64, 4, 32), dim3(32, 8), 0, stream>>>(Vb, VTb);
  fattn<<<dim3(512), dim3(256), 0, stream>>>(Qb, Kb, VTb, AO);
  gemm_bt<1><<<dim3(16, 32), dim3(256), 0, stream>>>(AO, WOb, bo, nullptr, nullptr,
                                                     nullptr, nullptr, nullptr, out);
}